// Round 1
// baseline (49.824 us; speedup 1.0000x reference)
//
#include <hip/hip_runtime.h>

#define SIZE_IN   4096
#define SIZE_OUT  4096
#define STEPS     8
#define IEC       512      // SIZE_IN / STEPS
#define GROUPS    8        // SIZE_OUT / IEC
#define BATCH     8192

#define C0_TILE         128
#define ROWS_PER_BLOCK  8
#define THREADS         256

// wc[g][k][c0] = W[g*IEC + c0][k*IEC + c0]   (the only 8 nonzeros per output row)
__global__ void sparse_compress_w(const float* __restrict__ W, float* __restrict__ wc) {
    int idx = blockIdx.x * blockDim.x + threadIdx.x;   // 0 .. GROUPS*STEPS*IEC-1
    int c0 = idx & (IEC - 1);
    int k  = (idx >> 9) & (STEPS - 1);
    int g  = idx >> 12;
    int row = g * IEC + c0;
    int col = k * IEC + c0;
    wc[idx] = W[(size_t)row * SIZE_IN + col];
}

__global__ __launch_bounds__(THREADS) void sparse_mm(
        const float* __restrict__ x, const float* __restrict__ wc,
        const float* __restrict__ bias, float* __restrict__ out) {
    __shared__ float lw[GROUPS * STEPS * C0_TILE];   // 32 KB: [g*STEPS+k][c0local]
    const int bx  = blockIdx.x;          // c0 tile index, 0..3
    const int by  = blockIdx.y;          // batch-row chunk, 0..1023
    const int tid = threadIdx.x;

    // Stage the 32 KB compressed-weight tile for this c0 range into LDS.
    const float4* wc4 = (const float4*)wc;
    float4*       lw4 = (float4*)lw;
    #pragma unroll
    for (int i = 0; i < 8; ++i) {
        int flat4 = i * THREADS + tid;          // 0..2047 float4s
        int gk = flat4 >> 5;                    // which [g][k] row (32 float4 per row)
        int c4 = flat4 & 31;                    // float4 within the tile row
        lw4[flat4] = wc4[gk * (IEC / 4) + bx * (C0_TILE / 4) + c4];
    }
    __syncthreads();

    const int r    = tid >> 5;                  // 0..7 local batch row
    const int lane = tid & 31;                  // 0..31 -> float4 within c0 tile
    const int b    = by * ROWS_PER_BLOCK + r;
    const int c0   = bx * C0_TILE + lane * 4;

    // 8 x-values per c0 (k = 0..7), shared by the 8 outputs g = 0..7.
    const float4* xrow = (const float4*)(x + (size_t)b * SIZE_IN);
    float4 xv[STEPS];
    #pragma unroll
    for (int k = 0; k < STEPS; ++k)
        xv[k] = xrow[(k * IEC + c0) >> 2];

    float4*       orow = (float4*)(out + (size_t)b * SIZE_OUT);
    const float4* b4   = (const float4*)bias;
    #pragma unroll
    for (int g = 0; g < GROUPS; ++g) {
        float4 acc = b4[(g * IEC + c0) >> 2];
        #pragma unroll
        for (int k = 0; k < STEPS; ++k) {
            const float4 w = *(const float4*)&lw[(g * STEPS + k) * C0_TILE + lane * 4];
            acc.x += xv[k].x * w.x;
            acc.y += xv[k].y * w.y;
            acc.z += xv[k].z * w.z;
            acc.w += xv[k].w * w.w;
        }
        orow[(g * IEC + c0) >> 2] = acc;
    }
}

extern "C" void kernel_launch(void* const* d_in, const int* in_sizes, int n_in,
                              void* d_out, int out_size, void* d_ws, size_t ws_size,
                              hipStream_t stream) {
    const float* x    = (const float*)d_in[0];
    const float* W    = (const float*)d_in[1];
    const float* bias = (const float*)d_in[2];
    // d_in[3] is the mask; its pattern is fixed and baked into the kernels.
    float* out = (float*)d_out;
    float* wc  = (float*)d_ws;                  // 128 KB compressed weights

    hipLaunchKernelGGL(sparse_compress_w,
                       dim3(GROUPS * STEPS * IEC / 256), dim3(256), 0, stream, W, wc);

    dim3 grid(IEC / C0_TILE, BATCH / ROWS_PER_BLOCK);   // (4, 1024)
    hipLaunchKernelGGL(sparse_mm, grid, dim3(THREADS), 0, stream, x, wc, bias, out);
}